// Round 14
// baseline (260.852 us; speedup 1.0000x reference)
//
#include <hip/hip_runtime.h>
#include <hip/hip_bf16.h>
#include <stdint.h>

// ---------------------------------------------------------------------------
// LocalAttentionBlock: B=2, L=2048, D=2048, H=16 (MQA, 1 KV head), hd=128,
// rope dims=64, window=512.
// R16: last untested GEMM-matrix cell: DBUF x 64x128 tile. R8 tested dbuf
// only at 128^2 (64KB LDS -> occupancy 31->23%, confounded). Here dbuf costs
// 48KB -> 3 blocks/CU cap = measured residency, occupancy-neutral; barriers
// halve (1/iter); the vmcnt drain overlaps the prev tile's compute. attn =
// R11 8-wave; prep = R15 vectorized. Disambiguates drain-bound vs issue-bound.
// ---------------------------------------------------------------------------

typedef float  f32x4  __attribute__((ext_vector_type(4)));
typedef __bf16 bf16x8 __attribute__((ext_vector_type(8)));

#define ASYNC_LD16(gp, lp)                                                     \
  __builtin_amdgcn_global_load_lds(                                            \
      (__attribute__((address_space(1))) void*)(gp),                           \
      (__attribute__((address_space(3))) void*)(lp), 16, 0, 0)

// ---------------------------------------------------------------------------
// Fused prep: blocks [0,8192) convert x -> bf16; blocks [8192,16896) do the
// four weight transposes (fp32 [R][C] -> bf16 [C][R]), float4-vectorized.
// ---------------------------------------------------------------------------
__global__ __launch_bounds__(256) void prep_all(
    const float* __restrict__ x, __hip_bfloat16* __restrict__ xb,
    const float* __restrict__ Wq, const float* __restrict__ Wk,
    const float* __restrict__ Wv, const float* __restrict__ Wo,
    __hip_bfloat16* __restrict__ wqkvT, __hip_bfloat16* __restrict__ woT) {
  __shared__ float t[32][33];
  int bid = blockIdx.x;
  if (bid < 8192) {
    const int i = bid * 256 + threadIdx.x;
    const float4 v = ((const float4*)x)[i];
    __align__(8) __hip_bfloat16 o[4] = {
        __float2bfloat16(v.x), __float2bfloat16(v.y),
        __float2bfloat16(v.z), __float2bfloat16(v.w)};
    *(uint2*)(xb + (size_t)i * 4) = *(uint2*)o;
    return;
  }
  bid -= 8192;
  const float* src;
  __hip_bfloat16* dst;
  int C, cb, rb;
  if (bid < 4096) {
    src = Wq; dst = wqkvT; C = 2048; cb = bid & 63; rb = bid >> 6;
  } else if (bid < 4352) {
    const int l = bid - 4096;
    src = Wk; dst = wqkvT + 2048ull * 2048; C = 128; cb = l & 3; rb = l >> 2;
  } else if (bid < 4608) {
    const int l = bid - 4352;
    src = Wv; dst = wqkvT + 2176ull * 2048; C = 128; cb = l & 3; rb = l >> 2;
  } else {
    const int l = bid - 4608;
    src = Wo; dst = woT; C = 2048; cb = l & 63; rb = l >> 6;
  }
  const int c0 = cb * 32, r0 = rb * 32;
  const int r8 = threadIdx.x >> 3;        // row in tile, 8 threads/row
  const int c4 = (threadIdx.x & 7) << 2;  // col start (x4)
  const float4 v4 = *(const float4*)&src[(size_t)(r0 + r8) * C + c0 + c4];
  t[r8][c4 + 0] = v4.x;
  t[r8][c4 + 1] = v4.y;
  t[r8][c4 + 2] = v4.z;
  t[r8][c4 + 3] = v4.w;
  __syncthreads();
  __align__(8) __hip_bfloat16 o4[4];
  o4[0] = __float2bfloat16(t[c4 + 0][r8]);
  o4[1] = __float2bfloat16(t[c4 + 1][r8]);
  o4[2] = __float2bfloat16(t[c4 + 2][r8]);
  o4[3] = __float2bfloat16(t[c4 + 3][r8]);
  *(uint2*)&dst[(size_t)(c0 + r8) * 2048 + r0 + c4] = *(uint2*)o4;
}

// Bijective XCD swizzle (grid % 8 == 0: 1152 and 1024).
__device__ __forceinline__ void xcd_remap(int& bx, int& by) {
  const int nwg = gridDim.x * gridDim.y;
  const int flat = blockIdx.y * gridDim.x + blockIdx.x;
  const int cpx = nwg >> 3;
  const int nid = (flat & 7) * cpx + (flat >> 3);
  bx = nid % gridDim.x;
  by = nid / gridDim.x;
}

// ---------------------------------------------------------------------------
// R16 GEMM core: 64x128 tile, 4 waves, BK=64, DOUBLE-BUFFERED (48 KB LDS).
// Per iter: ONE barrier (drains tile-t loads, frees buf^1) -> stage t+1 into
// buf^1 -> ds_read/MFMA tile t from buf. Drain overlaps compute.
// XOR chunk swizzle (measured zero conflicts) kept on both sides.
// ---------------------------------------------------------------------------
__device__ __forceinline__ void gemm_core64_db(const __bf16* __restrict__ A,
                                               const __bf16* __restrict__ BT,
                                               int K, int m0, int n0,
                                               __bf16* As, __bf16* Bs,
                                               f32x4 (&acc)[2][4]) {
  const int tid = threadIdx.x;
  const int wave = tid >> 6;          // 0..3
  const int lane = tid & 63;
  const int wm = (wave & 1) * 32;     // row group (0/32)
  const int wn = (wave >> 1) * 64;    // col group (0/64)
  const int ln = lane & 15;
  const int quad = lane >> 4;
  const int rdoff = (quad ^ ((ln >> 1) & 3)) * 8;

  size_t goffA[2];
  int ldsoffA[2];
#pragma unroll
  for (int i = 0; i < 2; i++) {
    const int cidx = (wave * 2 + i) * 64 + lane;  // [0,512)
    const int p = cidx >> 8;                      // k-panel 0/1
    const int pidx = cidx & 255;
    const int row = pidx >> 2;                    // [0,64)
    const int cc = pidx & 3;                      // chunk slot
    const int cg = cc ^ ((row >> 1) & 3);         // swizzled source chunk
    goffA[i] = (size_t)row * K + p * 32 + cg * 8;
    ldsoffA[i] = (wave * 2 + i) * 512;
  }
  size_t goffB[4];
  int ldsoffB[4];
#pragma unroll
  for (int i = 0; i < 4; i++) {
    const int cidx = (wave * 4 + i) * 64 + lane;  // [0,1024)
    const int p = cidx >> 9;
    const int pidx = cidx & 511;
    const int row = pidx >> 2;                    // [0,128)
    const int cc = pidx & 3;
    const int cg = cc ^ ((row >> 1) & 3);
    goffB[i] = (size_t)row * K + p * 32 + cg * 8;
    ldsoffB[i] = (wave * 4 + i) * 512;
  }
  const __bf16* Abase = A + (size_t)m0 * K;
  const __bf16* Bbase = BT + (size_t)n0 * K;
  const int NT = K >> 6;

  // prologue: stage tile 0 into buffer 0
#pragma unroll
  for (int i = 0; i < 2; i++) ASYNC_LD16(Abase + goffA[i], As + ldsoffA[i]);
#pragma unroll
  for (int i = 0; i < 4; i++) ASYNC_LD16(Bbase + goffB[i], Bs + ldsoffB[i]);

  int cur = 0;
  for (int t = 0; t < NT; ++t) {
    __syncthreads();  // tile t resident in buf[cur]; buf[cur^1] free
    if (t + 1 < NT) {
      const int k0 = (t + 1) << 6;
      __bf16* an = As + ((cur ^ 1) << 12);   // 4096 elems per A buf
      __bf16* bn = Bs + ((cur ^ 1) << 13);   // 8192 elems per B buf
#pragma unroll
      for (int i = 0; i < 2; i++)
        ASYNC_LD16(Abase + k0 + goffA[i], an + ldsoffA[i]);
#pragma unroll
      for (int i = 0; i < 4; i++)
        ASYNC_LD16(Bbase + k0 + goffB[i], bn + ldsoffB[i]);
    }
    const __bf16* as_ = As + (cur << 12);
    const __bf16* bs_ = Bs + (cur << 13);
    bf16x8 af[2][2], bf[4][2];
#pragma unroll
    for (int i = 0; i < 2; i++)
#pragma unroll
      for (int p = 0; p < 2; p++)
        af[i][p] =
            *(const bf16x8*)&as_[p * 2048 + (wm + i * 16 + ln) * 32 + rdoff];
#pragma unroll
    for (int j = 0; j < 4; j++)
#pragma unroll
      for (int p = 0; p < 2; p++)
        bf[j][p] =
            *(const bf16x8*)&bs_[p * 4096 + (wn + j * 16 + ln) * 32 + rdoff];
#pragma unroll
    for (int p = 0; p < 2; p++)
#pragma unroll
      for (int i = 0; i < 2; i++)
#pragma unroll
        for (int j = 0; j < 4; j++)
          acc[i][j] = __builtin_amdgcn_mfma_f32_16x16x32_bf16(
              af[i][p], bf[j][p], acc[i][j], 0, 0, 0);
    cur ^= 1;
  }
}

// ---------------------------------------------------------------------------
// QKV GEMM, fused epilogues. N=2304: n0<2048 -> q head (rope), n0==2048 -> k
// (rope), n0==2176 -> v written TRANSPOSED to vtd [b][128][2048].
// ---------------------------------------------------------------------------
__global__ __launch_bounds__(256) void gemm_qkv(
    const __bf16* __restrict__ A, const __bf16* __restrict__ BT,
    __hip_bfloat16* __restrict__ qd, __hip_bfloat16* __restrict__ kd,
    __hip_bfloat16* __restrict__ vtd, int K) {
  __shared__ __align__(16) __bf16 As[2 * 4096];
  __shared__ __align__(16) __bf16 Bs[2 * 8192];
  int bx, by;
  xcd_remap(bx, by);
  const int m0 = by * 64;
  const int n0 = bx * 128;
  f32x4 acc[2][4];
  const f32x4 zero = {0.f, 0.f, 0.f, 0.f};
#pragma unroll
  for (int i = 0; i < 2; i++)
#pragma unroll
    for (int j = 0; j < 4; j++) acc[i][j] = zero;
  gemm_core64_db(A, BT, K, m0, n0, As, Bs, acc);

  const int tid = threadIdx.x;
  const int wave = tid >> 6;
  const int lane = tid & 63;
  const int quad = lane >> 4;
  const int ln = lane & 15;
  const int wm = (wave & 1) * 32;
  const int wn = (wave >> 1) * 64;

  if (n0 == 2176) {  // V: transposed write, no rope
    const int bb = m0 >> 11;
    const int mloc = m0 & 2047;
#pragma unroll
    for (int i = 0; i < 2; i++) {
      const int rb = mloc + wm + i * 16 + quad * 4;
#pragma unroll
      for (int j = 0; j < 4; j++) {
        const int col = wn + j * 16 + ln;
        __align__(8) __hip_bfloat16 t4[4];
#pragma unroll
        for (int r = 0; r < 4; r++) t4[r] = __float2bfloat16(acc[i][j][r]);
        *(uint2*)(vtd + ((size_t)(bb * 128 + col)) * 2048 + rb) = *(uint2*)t4;
      }
    }
    return;
  }

  __hip_bfloat16* dst;
  int dstride, dcol;
  if (n0 < 2048) {
    dst = qd; dstride = 2048; dcol = n0;
  } else {
    dst = kd; dstride = 128; dcol = 0;
  }
  const bool dorope = (wn == 0);
  float invf0 = 0.f, invf1 = 0.f;
  if (dorope) {
    invf0 = expf(-0.28782313662425574f * (float)ln);          // d = ln
    invf1 = expf(-0.28782313662425574f * (float)(16 + ln));   // d = 16+ln
  }

#pragma unroll
  for (int i = 0; i < 2; i++) {
#pragma unroll
    for (int r = 0; r < 4; r++) {
      const int row = m0 + wm + i * 16 + quad * 4 + r;
      float o0 = acc[i][0][r], o1 = acc[i][1][r];
      float o2 = acc[i][2][r], o3 = acc[i][3][r];
      if (dorope) {
        const float pos = (float)(row & 2047);
        float s0, c0, s1, c1;
        __sincosf(pos * invf0, &s0, &c0);
        __sincosf(pos * invf1, &s1, &c1);
        const float a0 = o0, b0 = o2, a1 = o1, b1 = o3;
        o0 = a0 * c0 - b0 * s0;
        o2 = a0 * s0 + b0 * c0;
        o1 = a1 * c1 - b1 * s1;
        o3 = a1 * s1 + b1 * c1;
      }
      __hip_bfloat16* rp = dst + (size_t)row * dstride + dcol + wn + ln;
      rp[0]  = __float2bfloat16(o0);
      rp[16] = __float2bfloat16(o1);
      rp[32] = __float2bfloat16(o2);
      rp[48] = __float2bfloat16(o3);
    }
  }
}

// ---------------------------------------------------------------------------
// Output GEMM: fp32 + bias epilogue.
// ---------------------------------------------------------------------------
__global__ __launch_bounds__(256) void gemm_out(
    const __bf16* __restrict__ A, const __bf16* __restrict__ BT,
    float* __restrict__ C, const float* __restrict__ bias, int N, int K) {
  __shared__ __align__(16) __bf16 As[2 * 4096];
  __shared__ __align__(16) __bf16 Bs[2 * 8192];
  int bx, by;
  xcd_remap(bx, by);
  const int m0 = by * 64;
  const int n0 = bx * 128;
  f32x4 acc[2][4];
  const f32x4 zero = {0.f, 0.f, 0.f, 0.f};
#pragma unroll
  for (int i = 0; i < 2; i++)
#pragma unroll
    for (int j = 0; j < 4; j++) acc[i][j] = zero;
  gemm_core64_db(A, BT, K, m0, n0, As, Bs, acc);

  const int tid = threadIdx.x;
  const int wave = tid >> 6;
  const int lane = tid & 63;
  const int wm = (wave & 1) * 32;
  const int wn = (wave >> 1) * 64;
  const int lrow = lane & 15;
#pragma unroll
  for (int j = 0; j < 4; j++) {
    const int col = n0 + wn + j * 16 + lrow;
    const float bv = bias[col];
#pragma unroll
    for (int i = 0; i < 2; i++) {
#pragma unroll
      for (int r = 0; r < 4; r++) {
        const int row = m0 + wm + i * 16 + (lane >> 4) * 4 + r;
        C[(size_t)row * N + col] = acc[i][j][r] + bv;
      }
    }
  }
}

// ---------------------------------------------------------------------------
// MFMA flash attention (R11): 8 waves / 512 threads, wave owns 16 Q-rows.
// K/V double-buffered, issue-early staging, ONE barrier per tile, setprio
// around MFMA, mask peel (t in {0,1,8,9}). XOR swizzle on all LDS surfaces.
// ---------------------------------------------------------------------------
__global__ __launch_bounds__(512) void attn_mfma(
    const __bf16* __restrict__ qb,   // [B*2048][2048]
    const __bf16* __restrict__ kb,   // [B*2048][128]
    const __bf16* __restrict__ vtb,  // [B][128][2048]
    __hip_bfloat16* __restrict__ o)  // [B*2048][2048]
{
  __shared__ __align__(16) __bf16 Ks[2][4][64 * 32];   // 32 KB
  __shared__ __align__(16) __bf16 Vs[2][2][128 * 32];  // 32 KB
  __shared__ __align__(16) __bf16 Ps[8][2][512];       // 16 KB
  const int tid = threadIdx.x;
  const int w = tid >> 6;          // 0..7, wave owns rows [w*16, w*16+16)
  const int lane = tid & 63;
  const int quad = lane >> 4;
  const int ln = lane & 15;
  const int bid = blockIdx.x;
  const int q0 = (bid & 15) * 128;
  const int h = (bid >> 4) & 15;
  const int b = bid >> 8;
  const int swr = (ln >> 1) & 3;               // read-side swizzle
  const int rdoff = (quad ^ swr) * 8;          // slot offset for b128 reads

  bf16x8 qf[4];
  {
    const __bf16* qrow =
        qb + ((size_t)(b * 2048 + q0 + w * 16 + ln)) * 2048 + h * 128;
#pragma unroll
    for (int ks = 0; ks < 4; ks++)
      qf[ks] = *(const bf16x8*)(qrow + ks * 32 + quad * 8);
  }

  f32x4 oacc[8];
  const f32x4 zero = {0.f, 0.f, 0.f, 0.f};
#pragma unroll
  for (int nb = 0; nb < 8; nb++) oacc[nb] = zero;
  float li[4] = {0.f, 0.f, 0.f, 0.f};
  const float scale = 0.08838834764831845f;  // 1/sqrt(128)

  const __bf16* kbase = kb + (size_t)b * 2048 * 128;
  const __bf16* vbase = vtb + (size_t)b * 128 * 2048;

  const int key4 = lane >> 2, uu = lane & 3;
  const int sw = (key4 >> 1) & 3;  // write-side swizzle: fetch chunk uu^sw

  auto stage_kv = [&](int t, int bufi) {
    const int jt = q0 - 512 + 64 * t;
#pragma unroll
    for (int i = 0; i < 4; ++i) {
      const int g = w * 4 + i;     // 0..31
      if (g < 16) {                // K chunk g
        const int ks = g & 3, keybase = (g >> 2) * 16;
        ASYNC_LD16(kbase + (size_t)(jt + keybase + key4) * 128 + ks * 32 +
                       (uu ^ sw) * 8,
                   &Ks[bufi][ks][keybase * 32]);
      } else {                     // V chunk g-16
        const int c = g - 16;
        const int p = c & 1, dbase = (c >> 1) * 16;
        ASYNC_LD16(vbase + (size_t)(dbase + key4) * 2048 + jt + p * 32 +
                       (uu ^ sw) * 8,
                   &Vs[bufi][p][dbase * 32]);
      }
    }
  };

#define SOFTMAX_BODY(MASKED)                                                   \
  _Pragma("unroll") for (int j = 0; j < 4; j++)                                \
  _Pragma("unroll") for (int r = 0; r < 4; r++) {                              \
    float v = sacc[j][r] * scale;                                              \
    if (MASKED) {                                                              \
      const int d0 = (w * 16 + quad * 4 + r) - (j * 16 + ln);                  \
      if (t <= 1 && d0 >= (t << 6)) v = -1e30f;                                \
      if (t >= 8 && d0 < ((t - 8) << 6)) v = -1e30f;                           \
    }                                                                          \
    v = fminf(v, 60.f);                                                        \
    const float p = __expf(v);                                                 \
    li[r] += p;                                                                \
    const int ch = (j & 1) * 2 + (ln >> 3);                                    \
    const int swp = (quad * 2 + (r >> 1)) & 3;                                 \
    Ps[w][j >> 1][(quad * 4 + r) * 32 + (ch ^ swp) * 8 + (ln & 7)] =           \
        (__bf16)p;                                                             \
  }

  const int tstart = (q0 >= 512) ? 0 : (512 - q0) / 64;
  int cur = 0;
  stage_kv(tstart, 0);
  for (int t = tstart; t < 10; ++t) {
    __syncthreads();  // tile t resident in buf[cur]; buf[cur^1] free
    if (t + 1 < 10) stage_kv(t + 1, cur ^ 1);

    // S = Q K^T : 4 col blocks x 4 k panels
    f32x4 sacc[4];
#pragma unroll
    for (int j = 0; j < 4; j++) sacc[j] = zero;
    __builtin_amdgcn_s_setprio(1);
#pragma unroll
    for (int j = 0; j < 4; j++)
#pragma unroll
      for (int ks = 0; ks < 4; ks++) {
        const bf16x8 kf =
            *(const bf16x8*)&Ks[cur][ks][(j * 16 + ln) * 32 + rdoff];
        sacc[j] = __builtin_amdgcn_mfma_f32_16x16x32_bf16(qf[ks], kf, sacc[j],
                                                          0, 0, 0);
      }
    __builtin_amdgcn_s_setprio(0);

    // scale + (mask) + exp -> Ps (swizzled); accumulate per-lane li
    if (t <= 1 || t >= 8) {
      SOFTMAX_BODY(1)
    } else {
      SOFTMAX_BODY(0)
    }

    const bf16x8 pf0 = *(const bf16x8*)&Ps[w][0][ln * 32 + rdoff];
    const bf16x8 pf1 = *(const bf16x8*)&Ps[w][1][ln * 32 + rdoff];
    __builtin_amdgcn_s_setprio(1);
#pragma unroll
    for (int nb = 0; nb < 8; nb++) {
      const bf16x8 vf0 =
          *(const bf16x8*)&Vs[cur][0][(nb * 16 + ln) * 32 + rdoff];
      const bf16x8 vf1 =
          *(const bf16x8*)&Vs[cur][1][(nb * 16 + ln) * 32 + rdoff];
      oacc[nb] = __builtin_amdgcn_mfma_f32_16x16x32_bf16(pf0, vf0, oacc[nb],
                                                         0, 0, 0);
      oacc[nb] = __builtin_amdgcn_mfma_f32_16x16x32_bf16(pf1, vf1, oacc[nb],
                                                         0, 0, 0);
    }
    __builtin_amdgcn_s_setprio(0);
    cur ^= 1;
  }
#undef SOFTMAX_BODY

#pragma unroll
  for (int off = 1; off < 16; off <<= 1)
#pragma unroll
    for (int r = 0; r < 4; r++) li[r] += __shfl_xor(li[r], off);

  __hip_bfloat16* obase =
      o + ((size_t)(b * 2048 + q0 + w * 16 + quad * 4)) * 2048 + h * 128 + ln;
#pragma unroll
  for (int r = 0; r < 4; r++) {
    const float inv = 1.0f / li[r];
#pragma unroll
    for (int nb = 0; nb < 8; nb++)
      obase[(size_t)r * 2048 + nb * 16] = __float2bfloat16(oacc[nb][r] * inv);
  }
}

// ---------------------------------------------------------------------------
extern "C" void kernel_launch(void* const* d_in, const int* in_sizes, int n_in,
                              void* d_out, int out_size, void* d_ws,
                              size_t ws_size, hipStream_t stream) {
  const float* x = (const float*)d_in[0];
  const float* Wq = (const float*)d_in[1];
  const float* Wk = (const float*)d_in[2];
  const float* Wv = (const float*)d_in[3];
  const float* Wo = (const float*)d_in[4];
  const float* bo = (const float*)d_in[5];
  float* out = (float*)d_out;

  char* w = (char*)d_ws;
  auto alloc = [&](size_t bytes) {
    void* p = (void*)w;
    w += (bytes + 255) & ~(size_t)255;
    return p;
  };
  __bf16* xb = (__bf16*)alloc(4096ull * 2048 * 2);
  __hip_bfloat16* wqkvT = (__hip_bfloat16*)alloc(2304ull * 2048 * 2);
  __hip_bfloat16* woT = (__hip_bfloat16*)alloc(2048ull * 2048 * 2);
  __hip_bfloat16* qbuf = (__hip_bfloat16*)alloc(4096ull * 2048 * 2);
  __hip_bfloat16* kbuf = (__hip_bfloat16*)alloc(4096ull * 128 * 2);
  __hip_bfloat16* vtb = (__hip_bfloat16*)alloc(4096ull * 128 * 2);
  __hip_bfloat16* attnb = (__hip_bfloat16*)xb;  // alias: xb dead after gemm_qkv

  prep_all<<<16896, 256, 0, stream>>>(x, (__hip_bfloat16*)xb, Wq, Wk, Wv, Wo,
                                      wqkvT, woT);

  gemm_qkv<<<dim3(18, 64), 256, 0, stream>>>(xb, (const __bf16*)wqkvT, qbuf,
                                             kbuf, vtb, 2048);

  attn_mfma<<<512, 512, 0, stream>>>((const __bf16*)qbuf, (const __bf16*)kbuf,
                                     (const __bf16*)vtb, attnb);

  gemm_out<<<dim3(16, 64), 256, 0, stream>>>((const __bf16*)attnb,
                                             (const __bf16*)woT, out, bo, 2048,
                                             2048);
}

// Round 15
// 241.452 us; speedup vs baseline: 1.0803x; 1.0803x over previous
//
#include <hip/hip_runtime.h>
#include <hip/hip_bf16.h>
#include <stdint.h>

// ---------------------------------------------------------------------------
// LocalAttentionBlock: B=2, L=2048, D=2048, H=16 (MQA, 1 KV head), hd=128,
// rope dims=64, window=512.
// R17 = revert to R15 (best measured: 248.8 us). R16's dbuf 64x128 cell
// closed the GEMM structure matrix (all variants 59-62 us; sbuf 2-barrier
// 64x128 4-wave is the optimum at this grid size). GEMMs: R9 core + XCD
// remap. attn: R11 8-wave QBLK=128. prep: vectorized transposes.
// ---------------------------------------------------------------------------

typedef float  f32x4  __attribute__((ext_vector_type(4)));
typedef __bf16 bf16x8 __attribute__((ext_vector_type(8)));

#define ASYNC_LD16(gp, lp)                                                     \
  __builtin_amdgcn_global_load_lds(                                            \
      (__attribute__((address_space(1))) void*)(gp),                           \
      (__attribute__((address_space(3))) void*)(lp), 16, 0, 0)

// ---------------------------------------------------------------------------
// Fused prep: blocks [0,8192) convert x -> bf16; blocks [8192,16896) do the
// four weight transposes (fp32 [R][C] -> bf16 [C][R]), float4-vectorized.
// ---------------------------------------------------------------------------
__global__ __launch_bounds__(256) void prep_all(
    const float* __restrict__ x, __hip_bfloat16* __restrict__ xb,
    const float* __restrict__ Wq, const float* __restrict__ Wk,
    const float* __restrict__ Wv, const float* __restrict__ Wo,
    __hip_bfloat16* __restrict__ wqkvT, __hip_bfloat16* __restrict__ woT) {
  __shared__ float t[32][33];
  int bid = blockIdx.x;
  if (bid < 8192) {
    const int i = bid * 256 + threadIdx.x;
    const float4 v = ((const float4*)x)[i];
    __align__(8) __hip_bfloat16 o[4] = {
        __float2bfloat16(v.x), __float2bfloat16(v.y),
        __float2bfloat16(v.z), __float2bfloat16(v.w)};
    *(uint2*)(xb + (size_t)i * 4) = *(uint2*)o;
    return;
  }
  bid -= 8192;
  const float* src;
  __hip_bfloat16* dst;
  int C, cb, rb;
  if (bid < 4096) {
    src = Wq; dst = wqkvT; C = 2048; cb = bid & 63; rb = bid >> 6;
  } else if (bid < 4352) {
    const int l = bid - 4096;
    src = Wk; dst = wqkvT + 2048ull * 2048; C = 128; cb = l & 3; rb = l >> 2;
  } else if (bid < 4608) {
    const int l = bid - 4352;
    src = Wv; dst = wqkvT + 2176ull * 2048; C = 128; cb = l & 3; rb = l >> 2;
  } else {
    const int l = bid - 4608;
    src = Wo; dst = woT; C = 2048; cb = l & 63; rb = l >> 6;
  }
  const int c0 = cb * 32, r0 = rb * 32;
  const int r8 = threadIdx.x >> 3;        // row in tile, 8 threads/row
  const int c4 = (threadIdx.x & 7) << 2;  // col start (x4)
  const float4 v4 = *(const float4*)&src[(size_t)(r0 + r8) * C + c0 + c4];
  t[r8][c4 + 0] = v4.x;
  t[r8][c4 + 1] = v4.y;
  t[r8][c4 + 2] = v4.z;
  t[r8][c4 + 3] = v4.w;
  __syncthreads();
  __align__(8) __hip_bfloat16 o4[4];
  o4[0] = __float2bfloat16(t[c4 + 0][r8]);
  o4[1] = __float2bfloat16(t[c4 + 1][r8]);
  o4[2] = __float2bfloat16(t[c4 + 2][r8]);
  o4[3] = __float2bfloat16(t[c4 + 3][r8]);
  *(uint2*)&dst[(size_t)(c0 + r8) * 2048 + r0 + c4] = *(uint2*)o4;
}

// Bijective XCD swizzle (grid % 8 == 0: 1152 and 1024).
__device__ __forceinline__ void xcd_remap(int& bx, int& by) {
  const int nwg = gridDim.x * gridDim.y;
  const int flat = blockIdx.y * gridDim.x + blockIdx.x;
  const int cpx = nwg >> 3;
  const int nid = (flat & 7) * cpx + (flat >> 3);
  bx = nid % gridDim.x;
  by = nid / gridDim.x;
}

// ---------------------------------------------------------------------------
// R9 GEMM core: 64x128 tile (M x N), 4 waves (256 thr), each wave 32x64
// (acc[2][4]). BK=64 as two 32-k panels. LDS: A 8 KB + B 16 KB, XOR chunk
// swizzle (measured zero conflicts). Load -> sync -> compute -> sync.
// ---------------------------------------------------------------------------
__device__ __forceinline__ void gemm_core64(const __bf16* __restrict__ A,
                                            const __bf16* __restrict__ BT,
                                            int K, int m0, int n0, __bf16* As,
                                            __bf16* Bs, f32x4 (&acc)[2][4]) {
  const int tid = threadIdx.x;
  const int wave = tid >> 6;          // 0..3
  const int lane = tid & 63;
  const int wm = (wave & 1) * 32;     // row group (0/32)
  const int wn = (wave >> 1) * 64;    // col group (0/64)
  const int ln = lane & 15;
  const int quad = lane >> 4;
  const int rdoff = (quad ^ ((ln >> 1) & 3)) * 8;

  size_t goffA[2];
  int ldsoffA[2];
#pragma unroll
  for (int i = 0; i < 2; i++) {
    const int cidx = (wave * 2 + i) * 64 + lane;  // [0,512)
    const int p = cidx >> 8;                      // k-panel 0/1
    const int pidx = cidx & 255;
    const int row = pidx >> 2;                    // [0,64)
    const int cc = pidx & 3;                      // chunk slot
    const int cg = cc ^ ((row >> 1) & 3);         // swizzled source chunk
    goffA[i] = (size_t)row * K + p * 32 + cg * 8;
    ldsoffA[i] = (wave * 2 + i) * 512;
  }
  size_t goffB[4];
  int ldsoffB[4];
#pragma unroll
  for (int i = 0; i < 4; i++) {
    const int cidx = (wave * 4 + i) * 64 + lane;  // [0,1024)
    const int p = cidx >> 9;
    const int pidx = cidx & 511;
    const int row = pidx >> 2;                    // [0,128)
    const int cc = pidx & 3;
    const int cg = cc ^ ((row >> 1) & 3);
    goffB[i] = (size_t)row * K + p * 32 + cg * 8;
    ldsoffB[i] = (wave * 4 + i) * 512;
  }
  const __bf16* Abase = A + (size_t)m0 * K;
  const __bf16* Bbase = BT + (size_t)n0 * K;

  for (int k0 = 0; k0 < K; k0 += 64) {
#pragma unroll
    for (int i = 0; i < 2; i++)
      ASYNC_LD16(Abase + k0 + goffA[i], As + ldsoffA[i]);
#pragma unroll
    for (int i = 0; i < 4; i++)
      ASYNC_LD16(Bbase + k0 + goffB[i], Bs + ldsoffB[i]);
    __syncthreads();
    bf16x8 af[2][2], bf[4][2];
#pragma unroll
    for (int i = 0; i < 2; i++)
#pragma unroll
      for (int p = 0; p < 2; p++)
        af[i][p] = *(const bf16x8*)&As[p * 2048 + (wm + i * 16 + ln) * 32 + rdoff];
#pragma unroll
    for (int j = 0; j < 4; j++)
#pragma unroll
      for (int p = 0; p < 2; p++)
        bf[j][p] = *(const bf16x8*)&Bs[p * 4096 + (wn + j * 16 + ln) * 32 + rdoff];
#pragma unroll
    for (int p = 0; p < 2; p++)
#pragma unroll
      for (int i = 0; i < 2; i++)
#pragma unroll
        for (int j = 0; j < 4; j++)
          acc[i][j] = __builtin_amdgcn_mfma_f32_16x16x32_bf16(af[i][p], bf[j][p],
                                                              acc[i][j], 0, 0, 0);
    __syncthreads();
  }
}

// ---------------------------------------------------------------------------
// QKV GEMM, fused epilogues. N=2304: n0<2048 -> q head (rope), n0==2048 -> k
// (rope), n0==2176 -> v written TRANSPOSED to vtd [b][128][2048].
// ---------------------------------------------------------------------------
__global__ __launch_bounds__(256) void gemm_qkv(
    const __bf16* __restrict__ A, const __bf16* __restrict__ BT,
    __hip_bfloat16* __restrict__ qd, __hip_bfloat16* __restrict__ kd,
    __hip_bfloat16* __restrict__ vtd, int K) {
  __shared__ __align__(16) __bf16 As[2 * 2048];
  __shared__ __align__(16) __bf16 Bs[2 * 4096];
  int bx, by;
  xcd_remap(bx, by);
  const int m0 = by * 64;
  const int n0 = bx * 128;
  f32x4 acc[2][4];
  const f32x4 zero = {0.f, 0.f, 0.f, 0.f};
#pragma unroll
  for (int i = 0; i < 2; i++)
#pragma unroll
    for (int j = 0; j < 4; j++) acc[i][j] = zero;
  gemm_core64(A, BT, K, m0, n0, As, Bs, acc);

  const int tid = threadIdx.x;
  const int wave = tid >> 6;
  const int lane = tid & 63;
  const int quad = lane >> 4;
  const int ln = lane & 15;
  const int wm = (wave & 1) * 32;
  const int wn = (wave >> 1) * 64;

  if (n0 == 2176) {  // V: transposed write, no rope
    const int bb = m0 >> 11;
    const int mloc = m0 & 2047;
#pragma unroll
    for (int i = 0; i < 2; i++) {
      const int rb = mloc + wm + i * 16 + quad * 4;
#pragma unroll
      for (int j = 0; j < 4; j++) {
        const int col = wn + j * 16 + ln;
        __align__(8) __hip_bfloat16 t4[4];
#pragma unroll
        for (int r = 0; r < 4; r++) t4[r] = __float2bfloat16(acc[i][j][r]);
        *(uint2*)(vtd + ((size_t)(bb * 128 + col)) * 2048 + rb) = *(uint2*)t4;
      }
    }
    return;
  }

  __hip_bfloat16* dst;
  int dstride, dcol;
  if (n0 < 2048) {
    dst = qd; dstride = 2048; dcol = n0;
  } else {
    dst = kd; dstride = 128; dcol = 0;
  }
  const bool dorope = (wn == 0);
  float invf0 = 0.f, invf1 = 0.f;
  if (dorope) {
    invf0 = expf(-0.28782313662425574f * (float)ln);          // d = ln
    invf1 = expf(-0.28782313662425574f * (float)(16 + ln));   // d = 16+ln
  }

#pragma unroll
  for (int i = 0; i < 2; i++) {
#pragma unroll
    for (int r = 0; r < 4; r++) {
      const int row = m0 + wm + i * 16 + quad * 4 + r;
      float o0 = acc[i][0][r], o1 = acc[i][1][r];
      float o2 = acc[i][2][r], o3 = acc[i][3][r];
      if (dorope) {
        const float pos = (float)(row & 2047);
        float s0, c0, s1, c1;
        __sincosf(pos * invf0, &s0, &c0);
        __sincosf(pos * invf1, &s1, &c1);
        const float a0 = o0, b0 = o2, a1 = o1, b1 = o3;
        o0 = a0 * c0 - b0 * s0;
        o2 = a0 * s0 + b0 * c0;
        o1 = a1 * c1 - b1 * s1;
        o3 = a1 * s1 + b1 * c1;
      }
      __hip_bfloat16* rp = dst + (size_t)row * dstride + dcol + wn + ln;
      rp[0]  = __float2bfloat16(o0);
      rp[16] = __float2bfloat16(o1);
      rp[32] = __float2bfloat16(o2);
      rp[48] = __float2bfloat16(o3);
    }
  }
}

// ---------------------------------------------------------------------------
// Output GEMM: fp32 + bias epilogue.
// ---------------------------------------------------------------------------
__global__ __launch_bounds__(256) void gemm_out(
    const __bf16* __restrict__ A, const __bf16* __restrict__ BT,
    float* __restrict__ C, const float* __restrict__ bias, int N, int K) {
  __shared__ __align__(16) __bf16 As[2 * 2048];
  __shared__ __align__(16) __bf16 Bs[2 * 4096];
  int bx, by;
  xcd_remap(bx, by);
  const int m0 = by * 64;
  const int n0 = bx * 128;
  f32x4 acc[2][4];
  const f32x4 zero = {0.f, 0.f, 0.f, 0.f};
#pragma unroll
  for (int i = 0; i < 2; i++)
#pragma unroll
    for (int j = 0; j < 4; j++) acc[i][j] = zero;
  gemm_core64(A, BT, K, m0, n0, As, Bs, acc);

  const int tid = threadIdx.x;
  const int wave = tid >> 6;
  const int lane = tid & 63;
  const int wm = (wave & 1) * 32;
  const int wn = (wave >> 1) * 64;
  const int lrow = lane & 15;
#pragma unroll
  for (int j = 0; j < 4; j++) {
    const int col = n0 + wn + j * 16 + lrow;
    const float bv = bias[col];
#pragma unroll
    for (int i = 0; i < 2; i++) {
#pragma unroll
      for (int r = 0; r < 4; r++) {
        const int row = m0 + wm + i * 16 + (lane >> 4) * 4 + r;
        C[(size_t)row * N + col] = acc[i][j][r] + bv;
      }
    }
  }
}

// ---------------------------------------------------------------------------
// MFMA flash attention (R11): 8 waves / 512 threads, wave owns 16 Q-rows.
// K/V double-buffered, issue-early staging, ONE barrier per tile, setprio
// around MFMA, mask peel (t in {0,1,8,9}). XOR swizzle on all LDS surfaces.
// ---------------------------------------------------------------------------
__global__ __launch_bounds__(512) void attn_mfma(
    const __bf16* __restrict__ qb,   // [B*2048][2048]
    const __bf16* __restrict__ kb,   // [B*2048][128]
    const __bf16* __restrict__ vtb,  // [B][128][2048]
    __hip_bfloat16* __restrict__ o)  // [B*2048][2048]
{
  __shared__ __align__(16) __bf16 Ks[2][4][64 * 32];   // 32 KB
  __shared__ __align__(16) __bf16 Vs[2][2][128 * 32];  // 32 KB
  __shared__ __align__(16) __bf16 Ps[8][2][512];       // 16 KB
  const int tid = threadIdx.x;
  const int w = tid >> 6;          // 0..7, wave owns rows [w*16, w*16+16)
  const int lane = tid & 63;
  const int quad = lane >> 4;
  const int ln = lane & 15;
  const int bid = blockIdx.x;
  const int q0 = (bid & 15) * 128;
  const int h = (bid >> 4) & 15;
  const int b = bid >> 8;
  const int swr = (ln >> 1) & 3;               // read-side swizzle
  const int rdoff = (quad ^ swr) * 8;          // slot offset for b128 reads

  bf16x8 qf[4];
  {
    const __bf16* qrow =
        qb + ((size_t)(b * 2048 + q0 + w * 16 + ln)) * 2048 + h * 128;
#pragma unroll
    for (int ks = 0; ks < 4; ks++)
      qf[ks] = *(const bf16x8*)(qrow + ks * 32 + quad * 8);
  }

  f32x4 oacc[8];
  const f32x4 zero = {0.f, 0.f, 0.f, 0.f};
#pragma unroll
  for (int nb = 0; nb < 8; nb++) oacc[nb] = zero;
  float li[4] = {0.f, 0.f, 0.f, 0.f};
  const float scale = 0.08838834764831845f;  // 1/sqrt(128)

  const __bf16* kbase = kb + (size_t)b * 2048 * 128;
  const __bf16* vbase = vtb + (size_t)b * 128 * 2048;

  const int key4 = lane >> 2, uu = lane & 3;
  const int sw = (key4 >> 1) & 3;  // write-side swizzle: fetch chunk uu^sw

  auto stage_kv = [&](int t, int bufi) {
    const int jt = q0 - 512 + 64 * t;
#pragma unroll
    for (int i = 0; i < 4; ++i) {
      const int g = w * 4 + i;     // 0..31
      if (g < 16) {                // K chunk g
        const int ks = g & 3, keybase = (g >> 2) * 16;
        ASYNC_LD16(kbase + (size_t)(jt + keybase + key4) * 128 + ks * 32 +
                       (uu ^ sw) * 8,
                   &Ks[bufi][ks][keybase * 32]);
      } else {                     // V chunk g-16
        const int c = g - 16;
        const int p = c & 1, dbase = (c >> 1) * 16;
        ASYNC_LD16(vbase + (size_t)(dbase + key4) * 2048 + jt + p * 32 +
                       (uu ^ sw) * 8,
                   &Vs[bufi][p][dbase * 32]);
      }
    }
  };

#define SOFTMAX_BODY(MASKED)                                                   \
  _Pragma("unroll") for (int j = 0; j < 4; j++)                                \
  _Pragma("unroll") for (int r = 0; r < 4; r++) {                              \
    float v = sacc[j][r] * scale;                                              \
    if (MASKED) {                                                              \
      const int d0 = (w * 16 + quad * 4 + r) - (j * 16 + ln);                  \
      if (t <= 1 && d0 >= (t << 6)) v = -1e30f;                                \
      if (t >= 8 && d0 < ((t - 8) << 6)) v = -1e30f;                           \
    }                                                                          \
    v = fminf(v, 60.f);                                                        \
    const float p = __expf(v);                                                 \
    li[r] += p;                                                                \
    const int ch = (j & 1) * 2 + (ln >> 3);                                    \
    const int swp = (quad * 2 + (r >> 1)) & 3;                                 \
    Ps[w][j >> 1][(quad * 4 + r) * 32 + (ch ^ swp) * 8 + (ln & 7)] =           \
        (__bf16)p;                                                             \
  }

  const int tstart = (q0 >= 512) ? 0 : (512 - q0) / 64;
  int cur = 0;
  stage_kv(tstart, 0);
  for (int t = tstart; t < 10; ++t) {
    __syncthreads();  // tile t resident in buf[cur]; buf[cur^1] free
    if (t + 1 < 10) stage_kv(t + 1, cur ^ 1);

    // S = Q K^T : 4 col blocks x 4 k panels
    f32x4 sacc[4];
#pragma unroll
    for (int j = 0; j < 4; j++) sacc[j] = zero;
    __builtin_amdgcn_s_setprio(1);
#pragma unroll
    for (int j = 0; j < 4; j++)
#pragma unroll
      for (int ks = 0; ks < 4; ks++) {
        const bf16x8 kf =
            *(const bf16x8*)&Ks[cur][ks][(j * 16 + ln) * 32 + rdoff];
        sacc[j] = __builtin_amdgcn_mfma_f32_16x16x32_bf16(qf[ks], kf, sacc[j],
                                                          0, 0, 0);
      }
    __builtin_amdgcn_s_setprio(0);

    // scale + (mask) + exp -> Ps (swizzled); accumulate per-lane li
    if (t <= 1 || t >= 8) {
      SOFTMAX_BODY(1)
    } else {
      SOFTMAX_BODY(0)
    }

    const bf16x8 pf0 = *(const bf16x8*)&Ps[w][0][ln * 32 + rdoff];
    const bf16x8 pf1 = *(const bf16x8*)&Ps[w][1][ln * 32 + rdoff];
    __builtin_amdgcn_s_setprio(1);
#pragma unroll
    for (int nb = 0; nb < 8; nb++) {
      const bf16x8 vf0 =
          *(const bf16x8*)&Vs[cur][0][(nb * 16 + ln) * 32 + rdoff];
      const bf16x8 vf1 =
          *(const bf16x8*)&Vs[cur][1][(nb * 16 + ln) * 32 + rdoff];
      oacc[nb] = __builtin_amdgcn_mfma_f32_16x16x32_bf16(pf0, vf0, oacc[nb],
                                                         0, 0, 0);
      oacc[nb] = __builtin_amdgcn_mfma_f32_16x16x32_bf16(pf1, vf1, oacc[nb],
                                                         0, 0, 0);
    }
    __builtin_amdgcn_s_setprio(0);
    cur ^= 1;
  }
#undef SOFTMAX_BODY

#pragma unroll
  for (int off = 1; off < 16; off <<= 1)
#pragma unroll
    for (int r = 0; r < 4; r++) li[r] += __shfl_xor(li[r], off);

  __hip_bfloat16* obase =
      o + ((size_t)(b * 2048 + q0 + w * 16 + quad * 4)) * 2048 + h * 128 + ln;
#pragma unroll
  for (int r = 0; r < 4; r++) {
    const float inv = 1.0f / li[r];
#pragma unroll
    for (int nb = 0; nb < 8; nb++)
      obase[(size_t)r * 2048 + nb * 16] = __float2bfloat16(oacc[nb][r] * inv);
  }
}

// ---------------------------------------------------------------------------
extern "C" void kernel_launch(void* const* d_in, const int* in_sizes, int n_in,
                              void* d_out, int out_size, void* d_ws,
                              size_t ws_size, hipStream_t stream) {
  const float* x = (const float*)d_in[0];
  const float* Wq = (const float*)d_in[1];
  const float* Wk = (const float*)d_in[2];
  const float* Wv = (const float*)d_in[3];
  const float* Wo = (const float*)d_in[4];
  const float* bo = (const float*)d_in[5];
  float* out = (float*)d_out;

  char* w = (char*)d_ws;
  auto alloc = [&](size_t bytes) {
    void* p = (void*)w;
    w += (bytes + 255) & ~(size_t)255;
    return p;
  };
  __bf16* xb = (__bf16*)alloc(4096ull * 2048 * 2);
  __hip_bfloat16* wqkvT = (__hip_bfloat16*)alloc(2304ull * 2048 * 2);
  __hip_bfloat16* woT = (__hip_bfloat16*)alloc(2048ull * 2048 * 2);
  __hip_bfloat16* qbuf = (__hip_bfloat16*)alloc(4096ull * 2048 * 2);
  __hip_bfloat16* kbuf = (__hip_bfloat16*)alloc(4096ull * 128 * 2);
  __hip_bfloat16* vtb = (__hip_bfloat16*)alloc(4096ull * 128 * 2);
  __hip_bfloat16* attnb = (__hip_bfloat16*)xb;  // alias: xb dead after gemm_qkv

  prep_all<<<16896, 256, 0, stream>>>(x, (__hip_bfloat16*)xb, Wq, Wk, Wv, Wo,
                                      wqkvT, woT);

  gemm_qkv<<<dim3(18, 64), 256, 0, stream>>>(xb, (const __bf16*)wqkvT, qbuf,
                                             kbuf, vtb, 2048);

  attn_mfma<<<512, 512, 0, stream>>>((const __bf16*)qbuf, (const __bf16*)kbuf,
                                     (const __bf16*)vtb, attnb);

  gemm_out<<<dim3(16, 64), 256, 0, stream>>>((const __bf16*)attnb,
                                             (const __bf16*)woT, out, bo, 2048,
                                             2048);
}